// Round 10
// baseline (434.802 us; speedup 1.0000x reference)
//
#include <hip/hip_runtime.h>

// ---------------- problem constants ----------------
constexpr int NN   = 20000;   // nodes
constexpr int NE   = 160000;  // edges
constexpr int NG   = 32;      // graphs
constexpr int IN   = 27;
constexpr int HID  = 512;
constexpr int OUT  = 256;
constexpr int MPAD = 20096;   // 157*128 = 314*64
constexpr int MT64 = MPAD / 64;  // 314 m-tiles at BM=64

typedef unsigned short u16;
typedef __bf16 bf16x8 __attribute__((ext_vector_type(8)));
typedef float  f32x4  __attribute__((ext_vector_type(4)));
typedef u16    u16x8  __attribute__((ext_vector_type(8)));

__device__ __forceinline__ u16 f2b(float x) {
  __bf16 h = (__bf16)x;                 // RNE convert
  return __builtin_bit_cast(u16, h);
}
__device__ __forceinline__ float b2f(u16 u) {
  __bf16 h = __builtin_bit_cast(__bf16, u);
  return (float)h;
}

#define GLOBAL_AS __attribute__((address_space(1)))
#define LDS_AS    __attribute__((address_space(3)))
__device__ __forceinline__ void gload_lds16(const void* g, void* l) {
  __builtin_amdgcn_global_load_lds((const GLOBAL_AS void*)g, (LDS_AS void*)l, 16, 0, 0);
}

// ---------------- CSR build: single-block {LDS histogram + scan} ----------------
// Replaces memset(deg) + k_deg + old k_scan (3 nodes -> 1). 80 KiB static LDS
// (proven on gfx950 since round 6).
__global__ void k_scan(const int* __restrict__ edst, int* __restrict__ rowptr,
                       int* __restrict__ cursor, float* __restrict__ invdeg) {
  constexpr int CH = 20;                 // 1024 * 20 = 20480 >= NN
  __shared__ int sdeg[1024 * CH];
  __shared__ int wsum[16];
  const int tid = threadIdx.x;
  // zero histogram
  for (int j = tid; j < 1024 * CH; j += 1024) sdeg[j] = 0;
  __syncthreads();
  // LDS histogram of edge destinations (coalesced edge reads, ~8-way contention)
  for (int e = tid; e < NE; e += 1024) atomicAdd(&sdeg[edst[e]], 1);
  __syncthreads();
  const int i0 = tid * CH;
  int loc[CH];
  int sum = 0;
#pragma unroll
  for (int j = 0; j < CH; ++j) { loc[j] = sum; sum += sdeg[i0 + j]; }
  const int lane = tid & 63, wv = tid >> 6;
  int incl = sum;                        // wave-inclusive scan of chunk sums
#pragma unroll
  for (int off = 1; off < 64; off <<= 1) {
    int n = __shfl_up(incl, off);
    if (lane >= off) incl += n;
  }
  if (lane == 63) wsum[wv] = incl;
  __syncthreads();
  if (tid == 0) {
    int s = 0;
#pragma unroll
    for (int w = 0; w < 16; ++w) { int v = wsum[w]; wsum[w] = s + v; s += v; }
  }
  __syncthreads();
  const int wbase = (wv == 0) ? 0 : wsum[wv - 1];
  const int tbase = wbase + incl - sum;  // exclusive prefix of this chunk
#pragma unroll
  for (int j = 0; j < CH; ++j) {
    const int i = i0 + j;
    if (i < NN) {
      const int excl = tbase + loc[j];
      const int d = sdeg[i];
      rowptr[i] = excl;
      cursor[i] = excl;
      invdeg[i] = 1.0f / fmaxf((float)d, 1.0f);
    }
  }
  if (tid == 0) rowptr[NN] = wsum[15];
}

// ---------------- merged scatter + weight-convert (independent range-partitioned work)
constexpr int WC0 = 512 * 64;     // Bt0 elems   [512][64]   <- [Ws0;Wn0] padded
constexpr int WC1 = 512 * 1024;   // Bt1 elems   [512][1024] <- [Ws1;Wn1]
constexpr int WC2 = 256 * 1024;   // BtSN2 elems [256][1024] <- [Ws2;Wn2]
constexpr int WCT = WC0 + WC1 + WC2;
constexpr int SCT_BLK = (NE + 255) / 256;          // 625 scatter blocks
constexpr int WCV_BLK = (WCT + 255) / 256;         // 3200 wconv blocks
__global__ void k_scatter_wconv(const int* __restrict__ src, const int* __restrict__ dst,
                                int* __restrict__ cursor, int* __restrict__ ssrc,
                                const float* __restrict__ Ws0, const float* __restrict__ Wn0,
                                const float* __restrict__ Ws1, const float* __restrict__ Wn1,
                                const float* __restrict__ Ws2, const float* __restrict__ Wn2,
                                u16* __restrict__ Bt0, u16* __restrict__ Bt1,
                                u16* __restrict__ BtSN2) {
  const int b = blockIdx.x;
  if (b < SCT_BLK) {
    const int e = b * 256 + threadIdx.x;
    if (e < NE) {
      int p = atomicAdd(&cursor[dst[e]], 1);
      ssrc[p] = src[e];
    }
    return;
  }
  int idx = (b - SCT_BLK) * 256 + threadIdx.x;
  if (idx < WC0) {
    const int n = idx / 64, k = idx % 64;
    float v = 0.0f;
    if (k < IN)           v = Ws0[(size_t)k * 512 + n];
    else if (k < 2 * IN)  v = Wn0[(size_t)(k - IN) * 512 + n];
    Bt0[idx] = f2b(v);
    return;
  }
  idx -= WC0;
  if (idx < WC1) {
    const int n = idx / 1024, k = idx % 1024;
    const float v = (k < 512) ? Ws1[(size_t)k * 512 + n] : Wn1[(size_t)(k - 512) * 512 + n];
    Bt1[idx] = f2b(v);
    return;
  }
  idx -= WC1;
  if (idx < WC2) {
    const int n = idx / 1024, k = idx % 1024;
    const float v = (k < 512) ? Ws2[(size_t)k * 256 + n] : Wn2[(size_t)(k - 512) * 256 + n];
    BtSN2[idx] = f2b(v);
  }
}

// ---------------- A0 = [bf16(feature) | bf16(mean-agg(feature)) | zeros], [MPAD][64]
__global__ void k_build_A0(const float* __restrict__ feat, const int* __restrict__ rowptr,
                           const int* __restrict__ ssrc, const float* __restrict__ invdeg,
                           u16* __restrict__ A0) {
  const int r = blockIdx.x, t = threadIdx.x; // 64 threads
  u16* row = A0 + (size_t)r * 64;
  if (r >= NN) { row[t] = 0; return; }
  if (t < IN) {
    row[t] = f2b(feat[(size_t)r * IN + t]);
    float s = 0.0f;
    const int e0 = rowptr[r], e1 = rowptr[r + 1];
    int e = e0;
    for (; e + 1 < e1; e += 2) {         // 2-edge unroll: overlap gather latency
      const int s0 = ssrc[e], s1 = ssrc[e + 1];
      const float f0 = feat[(size_t)s0 * IN + t];
      const float f1 = feat[(size_t)s1 * IN + t];
      s += f0; s += f1;                  // sequential adds: FP order preserved
    }
    if (e < e1) s += feat[(size_t)ssrc[e] * IN + t];
    row[IN + t] = f2b(s * invdeg[r]);
  } else if (t >= 2 * IN) {
    row[t] = 0;
  }
}

// ---------------- agg over cols [0,512) of X[MPAD][1024] -> cols [512,1024)
// one WAVE per row (64 lanes x u16x8 = full 512 cols), 4 rows/block, 2-edge unroll
__global__ void k_agg512(u16* __restrict__ X, const int* __restrict__ rowptr,
                         const int* __restrict__ ssrc, const float* __restrict__ invdeg) {
  const int r = blockIdx.x * 4 + (threadIdx.x >> 6);
  if (r >= NN) return;
  const int lane = threadIdx.x & 63;
  float a[8] = {};
  const int e0 = rowptr[r], e1 = rowptr[r + 1];
  int e = e0;
  for (; e + 1 < e1; e += 2) {
    const int s0 = ssrc[e], s1 = ssrc[e + 1];
    const u16x8 v0 = *(const u16x8*)(X + (size_t)s0 * 1024 + lane * 8);
    const u16x8 v1 = *(const u16x8*)(X + (size_t)s1 * 1024 + lane * 8);
#pragma unroll
    for (int j = 0; j < 8; ++j) { a[j] += b2f(v0[j]); a[j] += b2f(v1[j]); }
  }
  if (e < e1) {
    const u16x8 v0 = *(const u16x8*)(X + (size_t)ssrc[e] * 1024 + lane * 8);
#pragma unroll
    for (int j = 0; j < 8; ++j) a[j] += b2f(v0[j]);
  }
  const float inv = invdeg[r];
  u16x8 o;
#pragma unroll
  for (int j = 0; j < 8; ++j) o[j] = f2b(a[j] * inv);
  *(u16x8*)(X + (size_t)r * 1024 + 512 + lane * 8) = o;
}

// ---------------- MFMA GEMM: D = A[MPAD][lda](bf16) x Bt[Nout][K](bf16)^T
// BM=64 x BN=128 tiles (latency-TLP regime: ~20 waves/CU; round-9 win, frozen).
// 4 waves in 2x2 quadrants, each wave 32x64 output (acc[2][4]).
// 1-D grid, XCD-grouped swizzle. flags: 1 = relu (bf16 out), 2 = fp32 out + row<NN guard
__global__ __launch_bounds__(256, 6) void k_gemm(
    const u16* __restrict__ A, int lda,
    const u16* __restrict__ Bt, int K,
    void* __restrict__ Out, int ldo,
    const float* __restrict__ bias,
    int flags, int nt) {
  __shared__ u16 As[64 * 64];    //  8 KiB
  __shared__ u16 Bs[128 * 64];   // 16 KiB
  const int tid = threadIdx.x;
  const int wid = tid >> 6, lane = tid & 63;
  const int l16 = lane & 15, lhi = lane >> 4;
  const int wr = wid >> 1, wc = wid & 1;

  // ---- XCD-grouped tile mapping (bijective; nt is a power of two) ----
  const int G    = gridDim.x;
  const int PER  = nt * 8;
  const int nOct = G / PER;              // full 8-Mtile groups
  const int base = nOct * PER;
  int x, y;
  if ((int)blockIdx.x < base) {
    x = (blockIdx.x & 7) + 8 * (blockIdx.x / PER);
    y = (blockIdx.x >> 3) & (nt - 1);
  } else {
    const int j = blockIdx.x - base;
    x = 8 * nOct + j / nt;
    y = j - (j / nt) * nt;
  }
  const int row0 = x * 64, col0 = y * 128;

  f32x4 acc[2][4] = {};

  for (int kt = 0; kt < K; kt += 64) {
    // stage A: 512 16B-slots (2/thread), B: 1024 slots (4/thread).
    // slot o -> row o>>3, slot o&7; global source slot XOR-swizzled so the
    // swizzled ds_read_b128 below sees linear data (rule 21).
#pragma unroll
    for (int p = 0; p < 2; ++p) {
      const int o = tid + p * 256;
      const int r = o >> 3, sl = o & 7;
      const int ss = sl ^ (r & 7);
      gload_lds16(A + (size_t)(row0 + r) * lda + kt + ss * 8,
                  &As[(wid * 64 + p * 256) * 8]);
    }
#pragma unroll
    for (int p = 0; p < 4; ++p) {
      const int o = tid + p * 256;
      const int r = o >> 3, sl = o & 7;
      const int ss = sl ^ (r & 7);
      gload_lds16(Bt + (size_t)(col0 + r) * K + kt + ss * 8,
                  &Bs[(wid * 64 + p * 256) * 8]);
    }
    __syncthreads();
#pragma unroll
    for (int ks = 0; ks < 2; ++ks) {
      bf16x8 af[2], bfr[4];
#pragma unroll
      for (int i = 0; i < 2; ++i) {
        const int r = wr * 32 + i * 16 + l16;
        const int s = (ks * 4 + lhi) ^ (r & 7);
        af[i] = *(const bf16x8*)&As[r * 64 + s * 8];
      }
#pragma unroll
      for (int n = 0; n < 4; ++n) {
        const int c = wc * 64 + n * 16 + l16;
        const int s = (ks * 4 + lhi) ^ (c & 7);
        bfr[n] = *(const bf16x8*)&Bs[c * 64 + s * 8];
      }
#pragma unroll
      for (int i = 0; i < 2; ++i)
#pragma unroll
        for (int n = 0; n < 4; ++n)
          acc[i][n] = __builtin_amdgcn_mfma_f32_16x16x32_bf16(af[i], bfr[n], acc[i][n], 0, 0, 0);
    }
    __syncthreads();
  }

  const bool relu = flags & 1;
  const bool f32o = flags & 2;
#pragma unroll
  for (int i = 0; i < 2; ++i) {
#pragma unroll
    for (int n = 0; n < 4; ++n) {
      const int C = col0 + wc * 64 + n * 16 + l16;
      const float bv = bias ? bias[C] : 0.0f;
#pragma unroll
      for (int q = 0; q < 4; ++q) {
        const int R = row0 + wr * 32 + i * 16 + lhi * 4 + q;
        float v = acc[i][n][q] + bv;
        if (f32o) {
          if (R < NN) ((float*)Out)[(size_t)R * ldo + C] = v;
        } else {
          if (relu) v = fmaxf(v, 0.0f);
          ((u16*)Out)[(size_t)R * ldo + C] = f2b(v);
        }
      }
    }
  }
}

// ---------------- pooling: one block per graph, direct write (no atomics, no memset)
__device__ __forceinline__ int lower_bound_g(const int* __restrict__ gid, int g) {
  int lo = 0, hi = NN;
  while (lo < hi) {
    const int mid = (lo + hi) >> 1;
    if (gid[mid] < g) lo = mid + 1; else hi = mid;
  }
  return lo;
}
__global__ void k_pool(const float* __restrict__ h, const int* __restrict__ gid,
                       float* __restrict__ hg) {
  __shared__ int s_n0, s_n1;
  const int g = blockIdx.x;
  const int t = threadIdx.x; // 256 = output col
  if (t == 0) { s_n0 = lower_bound_g(gid, g); s_n1 = lower_bound_g(gid, g + 1); }
  __syncthreads();
  const int n0 = s_n0, n1 = s_n1;
  float acc = 0.0f;
  for (int i = n0; i < n1; ++i) acc += h[(size_t)i * 256 + t];
  hg[g * 256 + t] = acc / fmaxf((float)(n1 - n0), 1.0f);
}

// ---------------- workspace layout (bytes) ----------------
constexpr size_t OFF_A0    = 0;                                   // [MPAD][64] bf16
constexpr size_t OFF_A1    = OFF_A0   + (size_t)MPAD * 64  * 2;   // [MPAD][1024] bf16 (h0|agg h0)
constexpr size_t OFF_A2    = OFF_A1   + (size_t)MPAD * 1024 * 2;  // [MPAD][1024] bf16 (h1|agg h1)
constexpr size_t OFF_BT0   = OFF_A2   + (size_t)MPAD * 1024 * 2;  // [512][64] bf16
constexpr size_t OFF_BT1   = OFF_BT0  + (size_t)512 * 64 * 2;     // [512][1024] bf16
constexpr size_t OFF_BTSN2 = OFF_BT1  + (size_t)512 * 1024 * 2;   // [256][1024] bf16
constexpr size_t OFF_RP    = OFF_BTSN2+ (size_t)256 * 1024 * 2;   // [NN+1] int
constexpr size_t OFF_CUR   = OFF_RP   + (size_t)(NN + 2) * 4;     // [NN] int
constexpr size_t OFF_SSRC  = OFF_CUR  + (size_t)NN * 4;           // [NE] int
constexpr size_t OFF_INVD  = OFF_SSRC + (size_t)NE * 4;           // [NN] float

extern "C" void kernel_launch(void* const* d_in, const int* in_sizes, int n_in,
                              void* d_out, int out_size, void* d_ws, size_t ws_size,
                              hipStream_t stream) {
  const float* feature = (const float*)d_in[0];
  const int*   esrc    = (const int*)d_in[1];
  const int*   edst    = (const int*)d_in[2];
  const int*   gid     = (const int*)d_in[3];
  const float* Ws0 = (const float*)d_in[4],  *Wn0 = (const float*)d_in[5],  *b0 = (const float*)d_in[6];
  const float* Ws1 = (const float*)d_in[7],  *Wn1 = (const float*)d_in[8],  *b1 = (const float*)d_in[9];
  const float* Ws2 = (const float*)d_in[10], *Wn2 = (const float*)d_in[11], *b2 = (const float*)d_in[12];

  char* ws = (char*)d_ws;
  u16*   A0    = (u16*)  (ws + OFF_A0);
  u16*   A1    = (u16*)  (ws + OFF_A1);
  u16*   A2    = (u16*)  (ws + OFF_A2);
  u16*   Bt0   = (u16*)  (ws + OFF_BT0);
  u16*   Bt1   = (u16*)  (ws + OFF_BT1);
  u16*   BtSN2 = (u16*)  (ws + OFF_BTSN2);
  int*   rp    = (int*)  (ws + OFF_RP);
  int*   cur   = (int*)  (ws + OFF_CUR);
  int*   ssrc  = (int*)  (ws + OFF_SSRC);
  float* invd  = (float*)(ws + OFF_INVD);

  float* out_h  = (float*)d_out;
  float* out_hg = out_h + (size_t)NN * OUT;

  // CSR by dst: single-block histogram+scan, then merged scatter+wconv
  k_scan<<<1, 1024, 0, stream>>>(edst, rp, cur, invd);
  k_scatter_wconv<<<SCT_BLK + WCV_BLK, 256, 0, stream>>>(
      esrc, edst, cur, ssrc, Ws0, Wn0, Ws1, Wn1, Ws2, Wn2, Bt0, Bt1, BtSN2);

  // layer 0: A0 = [f | agg(f)], h0 = relu(A0 @ [Ws0;Wn0] + b0) -> A1[:, :512]
  k_build_A0<<<MPAD, 64, 0, stream>>>(feature, rp, ssrc, invd, A0);
  k_gemm<<<MT64 * 4, 256, 0, stream>>>(A0, 64, Bt0, 64, A1, 1024, b0, 1, 4);

  // layer 1: agg(h0) -> A1[:, 512:], h1 = relu(A1 @ [Ws1;Wn1] + b1) -> A2[:, :512]
  k_agg512<<<(NN + 3) / 4, 256, 0, stream>>>(A1, rp, ssrc, invd);
  k_gemm<<<MT64 * 4, 256, 0, stream>>>(A1, 1024, Bt1, 1024, A2, 1024, b1, 1, 4);

  // layer 2 (fused by linearity): agg(h1) -> A2[:, 512:],
  // out = A2 @ [Ws2;Wn2] + b2   (== h1@Ws2 + mean_agg(h1)@Wn2 + b2)
  k_agg512<<<(NN + 3) / 4, 256, 0, stream>>>(A2, rp, ssrc, invd);
  k_gemm<<<MT64 * 2, 256, 0, stream>>>(A2, 1024, BtSN2, 1024, out_h, 256, b2, 2, 2);

  // avg pooling per graph (graph_ids sorted; one block per graph, direct write)
  k_pool<<<NG, 256, 0, stream>>>(out_h, gid, out_hg);
}

// Round 11
// 309.484 us; speedup vs baseline: 1.4049x; 1.4049x over previous
//
#include <hip/hip_runtime.h>

// ---------------- problem constants ----------------
constexpr int NN   = 20000;   // nodes
constexpr int NE   = 160000;  // edges
constexpr int NG   = 32;      // graphs
constexpr int IN   = 27;
constexpr int HID  = 512;
constexpr int OUT  = 256;
constexpr int MPAD = 20096;   // 157*128 = 314*64
constexpr int MT64 = MPAD / 64;  // 314 m-tiles at BM=64

typedef unsigned short u16;
typedef __bf16 bf16x8 __attribute__((ext_vector_type(8)));
typedef float  f32x4  __attribute__((ext_vector_type(4)));
typedef u16    u16x8  __attribute__((ext_vector_type(8)));

__device__ __forceinline__ u16 f2b(float x) {
  __bf16 h = (__bf16)x;                 // RNE convert
  return __builtin_bit_cast(u16, h);
}
__device__ __forceinline__ float b2f(u16 u) {
  __bf16 h = __builtin_bit_cast(__bf16, u);
  return (float)h;
}

#define GLOBAL_AS __attribute__((address_space(1)))
#define LDS_AS    __attribute__((address_space(3)))
__device__ __forceinline__ void gload_lds16(const void* g, void* l) {
  __builtin_amdgcn_global_load_lds((const GLOBAL_AS void*)g, (LDS_AS void*)l, 16, 0, 0);
}

// ---------------- CSR build: single-block {LDS histogram + scan} ----------------
__global__ void k_scan(const int* __restrict__ edst, int* __restrict__ rowptr,
                       int* __restrict__ cursor, float* __restrict__ invdeg) {
  constexpr int CH = 20;                 // 1024 * 20 = 20480 >= NN
  __shared__ int sdeg[1024 * CH];
  __shared__ int wsum[16];
  const int tid = threadIdx.x;
  // zero histogram
  for (int j = tid; j < 1024 * CH; j += 1024) sdeg[j] = 0;
  __syncthreads();
  // LDS histogram of edge destinations (coalesced edge reads)
  for (int e = tid; e < NE; e += 1024) atomicAdd(&sdeg[edst[e]], 1);
  __syncthreads();
  const int i0 = tid * CH;
  int loc[CH];
  int sum = 0;
#pragma unroll
  for (int j = 0; j < CH; ++j) { loc[j] = sum; sum += sdeg[i0 + j]; }
  const int lane = tid & 63, wv = tid >> 6;
  int incl = sum;                        // wave-inclusive scan of chunk sums
#pragma unroll
  for (int off = 1; off < 64; off <<= 1) {
    int n = __shfl_up(incl, off);
    if (lane >= off) incl += n;
  }
  if (lane == 63) wsum[wv] = incl;
  __syncthreads();
  if (tid == 0) {
    int s = 0;
#pragma unroll
    for (int w = 0; w < 16; ++w) { int v = wsum[w]; wsum[w] = s + v; s += v; }
  }
  __syncthreads();
  const int wbase = (wv == 0) ? 0 : wsum[wv - 1];
  const int tbase = wbase + incl - sum;  // exclusive prefix of this chunk
#pragma unroll
  for (int j = 0; j < CH; ++j) {
    const int i = i0 + j;
    if (i < NN) {
      const int excl = tbase + loc[j];
      const int d = sdeg[i];
      rowptr[i] = excl;
      cursor[i] = excl;
      invdeg[i] = 1.0f / fmaxf((float)d, 1.0f);
    }
  }
  if (tid == 0) rowptr[NN] = wsum[15];
}

// ---------------- merged scatter + weight-convert (independent range-partitioned work)
constexpr int WC0 = 512 * 64;     // Bt0 elems   [512][64]   <- [Ws0;Wn0] padded
constexpr int WC1 = 512 * 1024;   // Bt1 elems   [512][1024] <- [Ws1;Wn1]
constexpr int WC2 = 256 * 1024;   // BtSN2 elems [256][1024] <- [Ws2;Wn2]
constexpr int WCT = WC0 + WC1 + WC2;
constexpr int SCT_BLK = (NE + 255) / 256;          // 625 scatter blocks
constexpr int WCV_BLK = (WCT + 255) / 256;         // 3200 wconv blocks
__global__ void k_scatter_wconv(const int* __restrict__ src, const int* __restrict__ dst,
                                int* __restrict__ cursor, int* __restrict__ ssrc,
                                const float* __restrict__ Ws0, const float* __restrict__ Wn0,
                                const float* __restrict__ Ws1, const float* __restrict__ Wn1,
                                const float* __restrict__ Ws2, const float* __restrict__ Wn2,
                                u16* __restrict__ Bt0, u16* __restrict__ Bt1,
                                u16* __restrict__ BtSN2) {
  const int b = blockIdx.x;
  if (b < SCT_BLK) {
    const int e = b * 256 + threadIdx.x;
    if (e < NE) {
      int p = atomicAdd(&cursor[dst[e]], 1);
      ssrc[p] = src[e];
    }
    return;
  }
  int idx = (b - SCT_BLK) * 256 + threadIdx.x;
  if (idx < WC0) {
    const int n = idx / 64, k = idx % 64;
    float v = 0.0f;
    if (k < IN)           v = Ws0[(size_t)k * 512 + n];
    else if (k < 2 * IN)  v = Wn0[(size_t)(k - IN) * 512 + n];
    Bt0[idx] = f2b(v);
    return;
  }
  idx -= WC0;
  if (idx < WC1) {
    const int n = idx / 1024, k = idx % 1024;
    const float v = (k < 512) ? Ws1[(size_t)k * 512 + n] : Wn1[(size_t)(k - 512) * 512 + n];
    Bt1[idx] = f2b(v);
    return;
  }
  idx -= WC1;
  if (idx < WC2) {
    const int n = idx / 1024, k = idx % 1024;
    const float v = (k < 512) ? Ws2[(size_t)k * 256 + n] : Wn2[(size_t)(k - 512) * 256 + n];
    BtSN2[idx] = f2b(v);
  }
}

// ---------------- A0 = [bf16(feature) | bf16(mean-agg(feature)) | zeros], [MPAD][64]
__global__ void k_build_A0(const float* __restrict__ feat, const int* __restrict__ rowptr,
                           const int* __restrict__ ssrc, const float* __restrict__ invdeg,
                           u16* __restrict__ A0) {
  const int r = blockIdx.x, t = threadIdx.x; // 64 threads
  u16* row = A0 + (size_t)r * 64;
  if (r >= NN) { row[t] = 0; return; }
  if (t < IN) {
    row[t] = f2b(feat[(size_t)r * IN + t]);
    float s = 0.0f;
    const int e0 = rowptr[r], e1 = rowptr[r + 1];
    int e = e0;
    for (; e + 1 < e1; e += 2) {         // 2-edge unroll: overlap gather latency
      const int s0 = ssrc[e], s1 = ssrc[e + 1];
      const float f0 = feat[(size_t)s0 * IN + t];
      const float f1 = feat[(size_t)s1 * IN + t];
      s += f0; s += f1;                  // sequential adds: FP order preserved
    }
    if (e < e1) s += feat[(size_t)ssrc[e] * IN + t];
    row[IN + t] = f2b(s * invdeg[r]);
  } else if (t >= 2 * IN) {
    row[t] = 0;
  }
}

// ---------------- agg over cols [0,512) of X[MPAD][1024] -> cols [512,1024)
// one WAVE per row (64 lanes x u16x8 = full 512 cols), 4 rows/block, 2-edge unroll
__global__ void k_agg512(u16* __restrict__ X, const int* __restrict__ rowptr,
                         const int* __restrict__ ssrc, const float* __restrict__ invdeg) {
  const int r = blockIdx.x * 4 + (threadIdx.x >> 6);
  if (r >= NN) return;
  const int lane = threadIdx.x & 63;
  float a[8] = {};
  const int e0 = rowptr[r], e1 = rowptr[r + 1];
  int e = e0;
  for (; e + 1 < e1; e += 2) {
    const int s0 = ssrc[e], s1 = ssrc[e + 1];
    const u16x8 v0 = *(const u16x8*)(X + (size_t)s0 * 1024 + lane * 8);
    const u16x8 v1 = *(const u16x8*)(X + (size_t)s1 * 1024 + lane * 8);
#pragma unroll
    for (int j = 0; j < 8; ++j) { a[j] += b2f(v0[j]); a[j] += b2f(v1[j]); }
  }
  if (e < e1) {
    const u16x8 v0 = *(const u16x8*)(X + (size_t)ssrc[e] * 1024 + lane * 8);
#pragma unroll
    for (int j = 0; j < 8; ++j) a[j] += b2f(v0[j]);
  }
  const float inv = invdeg[r];
  u16x8 o;
#pragma unroll
  for (int j = 0; j < 8; ++j) o[j] = f2b(a[j] * inv);
  *(u16x8*)(X + (size_t)r * 1024 + 512 + lane * 8) = o;
}

// ---------------- MFMA GEMM: D = A[MPAD][lda](bf16) x Bt[Nout][K](bf16)^T
// BM=64 x BN=128 tiles (latency-TLP regime: ~20 waves/CU; round-9 win, frozen).
// 4 waves in 2x2 quadrants, each wave 32x64 output (acc[2][4]).
// 1-D grid, XCD-grouped swizzle. flags: 1 = relu (bf16 out), 2 = fp32 out + row<NN guard
__global__ __launch_bounds__(256, 6) void k_gemm(
    const u16* __restrict__ A, int lda,
    const u16* __restrict__ Bt, int K,
    void* __restrict__ Out, int ldo,
    const float* __restrict__ bias,
    int flags, int nt) {
  __shared__ u16 As[64 * 64];    //  8 KiB
  __shared__ u16 Bs[128 * 64];   // 16 KiB
  const int tid = threadIdx.x;
  const int wid = tid >> 6, lane = tid & 63;
  const int l16 = lane & 15, lhi = lane >> 4;
  const int wr = wid >> 1, wc = wid & 1;

  // ---- XCD-grouped tile mapping (bijective; nt is a power of two) ----
  const int G    = gridDim.x;
  const int PER  = nt * 8;
  const int nOct = G / PER;              // full 8-Mtile groups
  const int base = nOct * PER;
  int x, y;
  if ((int)blockIdx.x < base) {
    x = (blockIdx.x & 7) + 8 * (blockIdx.x / PER);
    y = (blockIdx.x >> 3) & (nt - 1);
  } else {
    const int j = blockIdx.x - base;
    x = 8 * nOct + j / nt;
    y = j - (j / nt) * nt;
  }
  const int row0 = x * 64, col0 = y * 128;

  f32x4 acc[2][4] = {};

  for (int kt = 0; kt < K; kt += 64) {
    // stage A: 512 16B-slots (2/thread), B: 1024 slots (4/thread).
    // slot o -> row o>>3, slot o&7; global source slot XOR-swizzled so the
    // swizzled ds_read_b128 below sees linear data (rule 21).
#pragma unroll
    for (int p = 0; p < 2; ++p) {
      const int o = tid + p * 256;
      const int r = o >> 3, sl = o & 7;
      const int ss = sl ^ (r & 7);
      gload_lds16(A + (size_t)(row0 + r) * lda + kt + ss * 8,
                  &As[(wid * 64 + p * 256) * 8]);
    }
#pragma unroll
    for (int p = 0; p < 4; ++p) {
      const int o = tid + p * 256;
      const int r = o >> 3, sl = o & 7;
      const int ss = sl ^ (r & 7);
      gload_lds16(Bt + (size_t)(col0 + r) * K + kt + ss * 8,
                  &Bs[(wid * 64 + p * 256) * 8]);
    }
    __syncthreads();
#pragma unroll
    for (int ks = 0; ks < 2; ++ks) {
      bf16x8 af[2], bfr[4];
#pragma unroll
      for (int i = 0; i < 2; ++i) {
        const int r = wr * 32 + i * 16 + l16;
        const int s = (ks * 4 + lhi) ^ (r & 7);
        af[i] = *(const bf16x8*)&As[r * 64 + s * 8];
      }
#pragma unroll
      for (int n = 0; n < 4; ++n) {
        const int c = wc * 64 + n * 16 + l16;
        const int s = (ks * 4 + lhi) ^ (c & 7);
        bfr[n] = *(const bf16x8*)&Bs[c * 64 + s * 8];
      }
#pragma unroll
      for (int i = 0; i < 2; ++i)
#pragma unroll
        for (int n = 0; n < 4; ++n)
          acc[i][n] = __builtin_amdgcn_mfma_f32_16x16x32_bf16(af[i], bfr[n], acc[i][n], 0, 0, 0);
    }
    __syncthreads();
  }

  const bool relu = flags & 1;
  const bool f32o = flags & 2;
#pragma unroll
  for (int i = 0; i < 2; ++i) {
#pragma unroll
    for (int n = 0; n < 4; ++n) {
      const int C = col0 + wc * 64 + n * 16 + l16;
      const float bv = bias ? bias[C] : 0.0f;
#pragma unroll
      for (int q = 0; q < 4; ++q) {
        const int R = row0 + wr * 32 + i * 16 + lhi * 4 + q;
        float v = acc[i][n][q] + bv;
        if (f32o) {
          if (R < NN) ((float*)Out)[(size_t)R * ldo + C] = v;
        } else {
          if (relu) v = fmaxf(v, 0.0f);
          ((u16*)Out)[(size_t)R * ldo + C] = f2b(v);
        }
      }
    }
  }
}

// ---------------- pooling (round-9 proven form: NG*8 blocks, pre-scaled atomics)
__device__ __forceinline__ int lower_bound_g(const int* __restrict__ gid, int g) {
  int lo = 0, hi = NN;
  while (lo < hi) {
    const int mid = (lo + hi) >> 1;
    if (gid[mid] < g) lo = mid + 1; else hi = mid;
  }
  return lo;
}
__global__ void k_pool(const float* __restrict__ h, const int* __restrict__ gid,
                       float* __restrict__ hg) {
  __shared__ int s_n0, s_n1;
  const int g = blockIdx.x >> 3, s = blockIdx.x & 7;
  const int t = threadIdx.x; // 256 = output col
  if (t == 0) { s_n0 = lower_bound_g(gid, g); s_n1 = lower_bound_g(gid, g + 1); }
  __syncthreads();
  const int n0 = s_n0, n1 = s_n1;
  const int len = n1 - n0, chunk = (len + 7) / 8;
  const int a = n0 + s * chunk;
  const int b = min(a + chunk, n1);
  float acc = 0.0f;
  for (int i = a; i < b; ++i) acc += h[(size_t)i * 256 + t];
  if (b > a) {
    const float inv = 1.0f / fmaxf((float)len, 1.0f);
    atomicAdd(&hg[g * 256 + t], acc * inv);
  }
}

// ---------------- workspace layout (bytes) ----------------
constexpr size_t OFF_A0    = 0;                                   // [MPAD][64] bf16
constexpr size_t OFF_A1    = OFF_A0   + (size_t)MPAD * 64  * 2;   // [MPAD][1024] bf16 (h0|agg h0)
constexpr size_t OFF_A2    = OFF_A1   + (size_t)MPAD * 1024 * 2;  // [MPAD][1024] bf16 (h1|agg h1)
constexpr size_t OFF_BT0   = OFF_A2   + (size_t)MPAD * 1024 * 2;  // [512][64] bf16
constexpr size_t OFF_BT1   = OFF_BT0  + (size_t)512 * 64 * 2;     // [512][1024] bf16
constexpr size_t OFF_BTSN2 = OFF_BT1  + (size_t)512 * 1024 * 2;   // [256][1024] bf16
constexpr size_t OFF_RP    = OFF_BTSN2+ (size_t)256 * 1024 * 2;   // [NN+1] int
constexpr size_t OFF_CUR   = OFF_RP   + (size_t)(NN + 2) * 4;     // [NN] int
constexpr size_t OFF_SSRC  = OFF_CUR  + (size_t)NN * 4;           // [NE] int
constexpr size_t OFF_INVD  = OFF_SSRC + (size_t)NE * 4;           // [NN] float

extern "C" void kernel_launch(void* const* d_in, const int* in_sizes, int n_in,
                              void* d_out, int out_size, void* d_ws, size_t ws_size,
                              hipStream_t stream) {
  const float* feature = (const float*)d_in[0];
  const int*   esrc    = (const int*)d_in[1];
  const int*   edst    = (const int*)d_in[2];
  const int*   gid     = (const int*)d_in[3];
  const float* Ws0 = (const float*)d_in[4],  *Wn0 = (const float*)d_in[5],  *b0 = (const float*)d_in[6];
  const float* Ws1 = (const float*)d_in[7],  *Wn1 = (const float*)d_in[8],  *b1 = (const float*)d_in[9];
  const float* Ws2 = (const float*)d_in[10], *Wn2 = (const float*)d_in[11], *b2 = (const float*)d_in[12];

  char* ws = (char*)d_ws;
  u16*   A0    = (u16*)  (ws + OFF_A0);
  u16*   A1    = (u16*)  (ws + OFF_A1);
  u16*   A2    = (u16*)  (ws + OFF_A2);
  u16*   Bt0   = (u16*)  (ws + OFF_BT0);
  u16*   Bt1   = (u16*)  (ws + OFF_BT1);
  u16*   BtSN2 = (u16*)  (ws + OFF_BTSN2);
  int*   rp    = (int*)  (ws + OFF_RP);
  int*   cur   = (int*)  (ws + OFF_CUR);
  int*   ssrc  = (int*)  (ws + OFF_SSRC);
  float* invd  = (float*)(ws + OFF_INVD);

  float* out_h  = (float*)d_out;
  float* out_hg = out_h + (size_t)NN * OUT;

  hipMemsetAsync(out_hg, 0, (size_t)NG * OUT * 4, stream);

  // CSR by dst: single-block histogram+scan, then merged scatter+wconv
  k_scan<<<1, 1024, 0, stream>>>(edst, rp, cur, invd);
  k_scatter_wconv<<<SCT_BLK + WCV_BLK, 256, 0, stream>>>(
      esrc, edst, cur, ssrc, Ws0, Wn0, Ws1, Wn1, Ws2, Wn2, Bt0, Bt1, BtSN2);

  // layer 0: A0 = [f | agg(f)], h0 = relu(A0 @ [Ws0;Wn0] + b0) -> A1[:, :512]
  k_build_A0<<<MPAD, 64, 0, stream>>>(feature, rp, ssrc, invd, A0);
  k_gemm<<<MT64 * 4, 256, 0, stream>>>(A0, 64, Bt0, 64, A1, 1024, b0, 1, 4);

  // layer 1: agg(h0) -> A1[:, 512:], h1 = relu(A1 @ [Ws1;Wn1] + b1) -> A2[:, :512]
  k_agg512<<<(NN + 3) / 4, 256, 0, stream>>>(A1, rp, ssrc, invd);
  k_gemm<<<MT64 * 4, 256, 0, stream>>>(A1, 1024, Bt1, 1024, A2, 1024, b1, 1, 4);

  // layer 2 (fused by linearity): agg(h1) -> A2[:, 512:],
  // out = A2 @ [Ws2;Wn2] + b2   (== h1@Ws2 + mean_agg(h1)@Wn2 + b2)
  k_agg512<<<(NN + 3) / 4, 256, 0, stream>>>(A2, rp, ssrc, invd);
  k_gemm<<<MT64 * 2, 256, 0, stream>>>(A2, 1024, BtSN2, 1024, out_h, 256, b2, 2, 2);

  // avg pooling per graph (graph_ids sorted; NG*8 blocks + pre-scaled atomics)
  k_pool<<<NG * 8, 256, 0, stream>>>(out_h, gid, out_hg);
}

// Round 12
// 286.025 us; speedup vs baseline: 1.5202x; 1.0820x over previous
//
#include <hip/hip_runtime.h>

// ---------------- problem constants ----------------
constexpr int NN   = 20000;   // nodes
constexpr int NE   = 160000;  // edges
constexpr int NG   = 32;      // graphs
constexpr int IN   = 27;
constexpr int HID  = 512;
constexpr int OUT  = 256;
constexpr int MPAD = 20096;   // 157*128 = 314*64
constexpr int MT64 = MPAD / 64;  // 314 m-tiles at BM=64

typedef unsigned short u16;
typedef __bf16 bf16x8 __attribute__((ext_vector_type(8)));
typedef float  f32x4  __attribute__((ext_vector_type(4)));
typedef u16    u16x8  __attribute__((ext_vector_type(8)));

__device__ __forceinline__ u16 f2b(float x) {
  __bf16 h = (__bf16)x;                 // RNE convert
  return __builtin_bit_cast(u16, h);
}
__device__ __forceinline__ float b2f(u16 u) {
  __bf16 h = __builtin_bit_cast(__bf16, u);
  return (float)h;
}

#define GLOBAL_AS __attribute__((address_space(1)))
#define LDS_AS    __attribute__((address_space(3)))
__device__ __forceinline__ void gload_lds16(const void* g, void* l) {
  __builtin_amdgcn_global_load_lds((const GLOBAL_AS void*)g, (LDS_AS void*)l, 16, 0, 0);
}

// ---------------- CSR build ----------------
// device-wide histogram (parallel, ~8-way mean contention on 20k counters)
__global__ void k_deg(const int* __restrict__ dst, int* __restrict__ deg) {
  int e = blockIdx.x * 256 + threadIdx.x;
  if (e < NE) atomicAdd(&deg[dst[e]], 1);
}

// single-block scan over deg[]: coalesced LDS stage + thread-serial chunks +
// wave shuffle scan (2 barriers). Proven ~5 µs form from rounds 6-9.
__global__ void k_scan(const int* __restrict__ deg, int* __restrict__ rowptr,
                       int* __restrict__ cursor, float* __restrict__ invdeg) {
  constexpr int CH = 20;                 // 1024 * 20 = 20480 >= NN
  __shared__ int sdeg[1024 * CH];
  __shared__ int wsum[16];
  const int tid = threadIdx.x;
  // coalesced global -> LDS
  for (int j = tid; j < 1024 * CH; j += 1024) sdeg[j] = (j < NN) ? deg[j] : 0;
  __syncthreads();
  const int i0 = tid * CH;
  int loc[CH];
  int sum = 0;
#pragma unroll
  for (int j = 0; j < CH; ++j) { loc[j] = sum; sum += sdeg[i0 + j]; }
  const int lane = tid & 63, wv = tid >> 6;
  int incl = sum;                        // wave-inclusive scan of chunk sums
#pragma unroll
  for (int off = 1; off < 64; off <<= 1) {
    int n = __shfl_up(incl, off);
    if (lane >= off) incl += n;
  }
  if (lane == 63) wsum[wv] = incl;
  __syncthreads();
  if (tid == 0) {
    int s = 0;
#pragma unroll
    for (int w = 0; w < 16; ++w) { int v = wsum[w]; wsum[w] = s + v; s += v; }
  }
  __syncthreads();
  const int wbase = (wv == 0) ? 0 : wsum[wv - 1];
  const int tbase = wbase + incl - sum;  // exclusive prefix of this chunk
#pragma unroll
  for (int j = 0; j < CH; ++j) {
    const int i = i0 + j;
    if (i < NN) {
      const int excl = tbase + loc[j];
      const int d = sdeg[i];
      rowptr[i] = excl;
      cursor[i] = excl;
      invdeg[i] = 1.0f / fmaxf((float)d, 1.0f);
    }
  }
  if (tid == 0) rowptr[NN] = wsum[15];
}

// ---------------- merged scatter + weight-convert (independent range-partitioned work)
constexpr int WC0 = 512 * 64;     // Bt0 elems   [512][64]   <- [Ws0;Wn0] padded
constexpr int WC1 = 512 * 1024;   // Bt1 elems   [512][1024] <- [Ws1;Wn1]
constexpr int WC2 = 256 * 1024;   // BtSN2 elems [256][1024] <- [Ws2;Wn2]
constexpr int WCT = WC0 + WC1 + WC2;
constexpr int SCT_BLK = (NE + 255) / 256;          // 625 scatter blocks
constexpr int WCV_BLK = (WCT + 255) / 256;         // 3200 wconv blocks
__global__ void k_scatter_wconv(const int* __restrict__ src, const int* __restrict__ dst,
                                int* __restrict__ cursor, int* __restrict__ ssrc,
                                const float* __restrict__ Ws0, const float* __restrict__ Wn0,
                                const float* __restrict__ Ws1, const float* __restrict__ Wn1,
                                const float* __restrict__ Ws2, const float* __restrict__ Wn2,
                                u16* __restrict__ Bt0, u16* __restrict__ Bt1,
                                u16* __restrict__ BtSN2) {
  const int b = blockIdx.x;
  if (b < SCT_BLK) {
    const int e = b * 256 + threadIdx.x;
    if (e < NE) {
      int p = atomicAdd(&cursor[dst[e]], 1);
      ssrc[p] = src[e];
    }
    return;
  }
  int idx = (b - SCT_BLK) * 256 + threadIdx.x;
  if (idx < WC0) {
    const int n = idx / 64, k = idx % 64;
    float v = 0.0f;
    if (k < IN)           v = Ws0[(size_t)k * 512 + n];
    else if (k < 2 * IN)  v = Wn0[(size_t)(k - IN) * 512 + n];
    Bt0[idx] = f2b(v);
    return;
  }
  idx -= WC0;
  if (idx < WC1) {
    const int n = idx / 1024, k = idx % 1024;
    const float v = (k < 512) ? Ws1[(size_t)k * 512 + n] : Wn1[(size_t)(k - 512) * 512 + n];
    Bt1[idx] = f2b(v);
    return;
  }
  idx -= WC1;
  if (idx < WC2) {
    const int n = idx / 1024, k = idx % 1024;
    const float v = (k < 512) ? Ws2[(size_t)k * 256 + n] : Wn2[(size_t)(k - 512) * 256 + n];
    BtSN2[idx] = f2b(v);
  }
}

// ---------------- A0 = [bf16(feature) | bf16(mean-agg(feature)) | zeros], [MPAD][64]
__global__ void k_build_A0(const float* __restrict__ feat, const int* __restrict__ rowptr,
                           const int* __restrict__ ssrc, const float* __restrict__ invdeg,
                           u16* __restrict__ A0) {
  const int r = blockIdx.x, t = threadIdx.x; // 64 threads
  u16* row = A0 + (size_t)r * 64;
  if (r >= NN) { row[t] = 0; return; }
  if (t < IN) {
    row[t] = f2b(feat[(size_t)r * IN + t]);
    float s = 0.0f;
    const int e0 = rowptr[r], e1 = rowptr[r + 1];
    int e = e0;
    for (; e + 1 < e1; e += 2) {         // 2-edge unroll: overlap gather latency
      const int s0 = ssrc[e], s1 = ssrc[e + 1];
      const float f0 = feat[(size_t)s0 * IN + t];
      const float f1 = feat[(size_t)s1 * IN + t];
      s += f0; s += f1;                  // sequential adds: FP order preserved
    }
    if (e < e1) s += feat[(size_t)ssrc[e] * IN + t];
    row[IN + t] = f2b(s * invdeg[r]);
  } else if (t >= 2 * IN) {
    row[t] = 0;
  }
}

// ---------------- agg over cols [0,512) of X[MPAD][1024] -> cols [512,1024)
// one WAVE per row (64 lanes x u16x8 = full 512 cols), 4 rows/block, 2-edge unroll
__global__ void k_agg512(u16* __restrict__ X, const int* __restrict__ rowptr,
                         const int* __restrict__ ssrc, const float* __restrict__ invdeg) {
  const int r = blockIdx.x * 4 + (threadIdx.x >> 6);
  if (r >= NN) return;
  const int lane = threadIdx.x & 63;
  float a[8] = {};
  const int e0 = rowptr[r], e1 = rowptr[r + 1];
  int e = e0;
  for (; e + 1 < e1; e += 2) {
    const int s0 = ssrc[e], s1 = ssrc[e + 1];
    const u16x8 v0 = *(const u16x8*)(X + (size_t)s0 * 1024 + lane * 8);
    const u16x8 v1 = *(const u16x8*)(X + (size_t)s1 * 1024 + lane * 8);
#pragma unroll
    for (int j = 0; j < 8; ++j) { a[j] += b2f(v0[j]); a[j] += b2f(v1[j]); }
  }
  if (e < e1) {
    const u16x8 v0 = *(const u16x8*)(X + (size_t)ssrc[e] * 1024 + lane * 8);
#pragma unroll
    for (int j = 0; j < 8; ++j) a[j] += b2f(v0[j]);
  }
  const float inv = invdeg[r];
  u16x8 o;
#pragma unroll
  for (int j = 0; j < 8; ++j) o[j] = f2b(a[j] * inv);
  *(u16x8*)(X + (size_t)r * 1024 + 512 + lane * 8) = o;
}

// ---------------- MFMA GEMM: D = A[MPAD][lda](bf16) x Bt[Nout][K](bf16)^T
// BM=64 x BN=128 tiles (latency-TLP regime: ~20 waves/CU; round-9 win, frozen).
// 4 waves in 2x2 quadrants, each wave 32x64 output (acc[2][4]).
// 1-D grid, XCD-grouped swizzle. flags: 1 = relu (bf16 out), 2 = fp32 out + row<NN guard
__global__ __launch_bounds__(256, 6) void k_gemm(
    const u16* __restrict__ A, int lda,
    const u16* __restrict__ Bt, int K,
    void* __restrict__ Out, int ldo,
    const float* __restrict__ bias,
    int flags, int nt) {
  __shared__ u16 As[64 * 64];    //  8 KiB
  __shared__ u16 Bs[128 * 64];   // 16 KiB
  const int tid = threadIdx.x;
  const int wid = tid >> 6, lane = tid & 63;
  const int l16 = lane & 15, lhi = lane >> 4;
  const int wr = wid >> 1, wc = wid & 1;

  // ---- XCD-grouped tile mapping (bijective; nt is a power of two) ----
  const int G    = gridDim.x;
  const int PER  = nt * 8;
  const int nOct = G / PER;              // full 8-Mtile groups
  const int base = nOct * PER;
  int x, y;
  if ((int)blockIdx.x < base) {
    x = (blockIdx.x & 7) + 8 * (blockIdx.x / PER);
    y = (blockIdx.x >> 3) & (nt - 1);
  } else {
    const int j = blockIdx.x - base;
    x = 8 * nOct + j / nt;
    y = j - (j / nt) * nt;
  }
  const int row0 = x * 64, col0 = y * 128;

  f32x4 acc[2][4] = {};

  for (int kt = 0; kt < K; kt += 64) {
    // stage A: 512 16B-slots (2/thread), B: 1024 slots (4/thread).
    // slot o -> row o>>3, slot o&7; global source slot XOR-swizzled so the
    // swizzled ds_read_b128 below sees linear data (rule 21).
#pragma unroll
    for (int p = 0; p < 2; ++p) {
      const int o = tid + p * 256;
      const int r = o >> 3, sl = o & 7;
      const int ss = sl ^ (r & 7);
      gload_lds16(A + (size_t)(row0 + r) * lda + kt + ss * 8,
                  &As[(wid * 64 + p * 256) * 8]);
    }
#pragma unroll
    for (int p = 0; p < 4; ++p) {
      const int o = tid + p * 256;
      const int r = o >> 3, sl = o & 7;
      const int ss = sl ^ (r & 7);
      gload_lds16(Bt + (size_t)(col0 + r) * K + kt + ss * 8,
                  &Bs[(wid * 64 + p * 256) * 8]);
    }
    __syncthreads();
#pragma unroll
    for (int ks = 0; ks < 2; ++ks) {
      bf16x8 af[2], bfr[4];
#pragma unroll
      for (int i = 0; i < 2; ++i) {
        const int r = wr * 32 + i * 16 + l16;
        const int s = (ks * 4 + lhi) ^ (r & 7);
        af[i] = *(const bf16x8*)&As[r * 64 + s * 8];
      }
#pragma unroll
      for (int n = 0; n < 4; ++n) {
        const int c = wc * 64 + n * 16 + l16;
        const int s = (ks * 4 + lhi) ^ (c & 7);
        bfr[n] = *(const bf16x8*)&Bs[c * 64 + s * 8];
      }
#pragma unroll
      for (int i = 0; i < 2; ++i)
#pragma unroll
        for (int n = 0; n < 4; ++n)
          acc[i][n] = __builtin_amdgcn_mfma_f32_16x16x32_bf16(af[i], bfr[n], acc[i][n], 0, 0, 0);
    }
    __syncthreads();
  }

  const bool relu = flags & 1;
  const bool f32o = flags & 2;
#pragma unroll
  for (int i = 0; i < 2; ++i) {
#pragma unroll
    for (int n = 0; n < 4; ++n) {
      const int C = col0 + wc * 64 + n * 16 + l16;
      const float bv = bias ? bias[C] : 0.0f;
#pragma unroll
      for (int q = 0; q < 4; ++q) {
        const int R = row0 + wr * 32 + i * 16 + lhi * 4 + q;
        float v = acc[i][n][q] + bv;
        if (f32o) {
          if (R < NN) ((float*)Out)[(size_t)R * ldo + C] = v;
        } else {
          if (relu) v = fmaxf(v, 0.0f);
          ((u16*)Out)[(size_t)R * ldo + C] = f2b(v);
        }
      }
    }
  }
}

// ---------------- pooling (NG*8 blocks, pre-scaled atomics) ----------------
__device__ __forceinline__ int lower_bound_g(const int* __restrict__ gid, int g) {
  int lo = 0, hi = NN;
  while (lo < hi) {
    const int mid = (lo + hi) >> 1;
    if (gid[mid] < g) lo = mid + 1; else hi = mid;
  }
  return lo;
}
__global__ void k_pool(const float* __restrict__ h, const int* __restrict__ gid,
                       float* __restrict__ hg) {
  __shared__ int s_n0, s_n1;
  const int g = blockIdx.x >> 3, s = blockIdx.x & 7;
  const int t = threadIdx.x; // 256 = output col
  if (t == 0) { s_n0 = lower_bound_g(gid, g); s_n1 = lower_bound_g(gid, g + 1); }
  __syncthreads();
  const int n0 = s_n0, n1 = s_n1;
  const int len = n1 - n0, chunk = (len + 7) / 8;
  const int a = n0 + s * chunk;
  const int b = min(a + chunk, n1);
  float acc = 0.0f;
  for (int i = a; i < b; ++i) acc += h[(size_t)i * 256 + t];
  if (b > a) {
    const float inv = 1.0f / fmaxf((float)len, 1.0f);
    atomicAdd(&hg[g * 256 + t], acc * inv);
  }
}

// ---------------- workspace layout (bytes) ----------------
constexpr size_t OFF_A0    = 0;                                   // [MPAD][64] bf16
constexpr size_t OFF_A1    = OFF_A0   + (size_t)MPAD * 64  * 2;   // [MPAD][1024] bf16 (h0|agg h0)
constexpr size_t OFF_A2    = OFF_A1   + (size_t)MPAD * 1024 * 2;  // [MPAD][1024] bf16 (h1|agg h1)
constexpr size_t OFF_BT0   = OFF_A2   + (size_t)MPAD * 1024 * 2;  // [512][64] bf16
constexpr size_t OFF_BT1   = OFF_BT0  + (size_t)512 * 64 * 2;     // [512][1024] bf16
constexpr size_t OFF_BTSN2 = OFF_BT1  + (size_t)512 * 1024 * 2;   // [256][1024] bf16
constexpr size_t OFF_DEG   = OFF_BTSN2+ (size_t)256 * 1024 * 2;   // [NN] int
constexpr size_t OFF_RP    = OFF_DEG  + (size_t)NN * 4;           // [NN+1] int
constexpr size_t OFF_CUR   = OFF_RP   + (size_t)(NN + 2) * 4;     // [NN] int
constexpr size_t OFF_SSRC  = OFF_CUR  + (size_t)NN * 4;           // [NE] int
constexpr size_t OFF_INVD  = OFF_SSRC + (size_t)NE * 4;           // [NN] float

extern "C" void kernel_launch(void* const* d_in, const int* in_sizes, int n_in,
                              void* d_out, int out_size, void* d_ws, size_t ws_size,
                              hipStream_t stream) {
  const float* feature = (const float*)d_in[0];
  const int*   esrc    = (const int*)d_in[1];
  const int*   edst    = (const int*)d_in[2];
  const int*   gid     = (const int*)d_in[3];
  const float* Ws0 = (const float*)d_in[4],  *Wn0 = (const float*)d_in[5],  *b0 = (const float*)d_in[6];
  const float* Ws1 = (const float*)d_in[7],  *Wn1 = (const float*)d_in[8],  *b1 = (const float*)d_in[9];
  const float* Ws2 = (const float*)d_in[10], *Wn2 = (const float*)d_in[11], *b2 = (const float*)d_in[12];

  char* ws = (char*)d_ws;
  u16*   A0    = (u16*)  (ws + OFF_A0);
  u16*   A1    = (u16*)  (ws + OFF_A1);
  u16*   A2    = (u16*)  (ws + OFF_A2);
  u16*   Bt0   = (u16*)  (ws + OFF_BT0);
  u16*   Bt1   = (u16*)  (ws + OFF_BT1);
  u16*   BtSN2 = (u16*)  (ws + OFF_BTSN2);
  int*   deg   = (int*)  (ws + OFF_DEG);
  int*   rp    = (int*)  (ws + OFF_RP);
  int*   cur   = (int*)  (ws + OFF_CUR);
  int*   ssrc  = (int*)  (ws + OFF_SSRC);
  float* invd  = (float*)(ws + OFF_INVD);

  float* out_h  = (float*)d_out;
  float* out_hg = out_h + (size_t)NN * OUT;

  hipMemsetAsync(deg,  0, (size_t)NN * 4, stream);
  hipMemsetAsync(out_hg, 0, (size_t)NG * OUT * 4, stream);

  // CSR by dst: parallel histogram, single-block scan, merged scatter+wconv
  k_deg <<<(NE + 255) / 256, 256, 0, stream>>>(edst, deg);
  k_scan<<<1, 1024, 0, stream>>>(deg, rp, cur, invd);
  k_scatter_wconv<<<SCT_BLK + WCV_BLK, 256, 0, stream>>>(
      esrc, edst, cur, ssrc, Ws0, Wn0, Ws1, Wn1, Ws2, Wn2, Bt0, Bt1, BtSN2);

  // layer 0: A0 = [f | agg(f)], h0 = relu(A0 @ [Ws0;Wn0] + b0) -> A1[:, :512]
  k_build_A0<<<MPAD, 64, 0, stream>>>(feature, rp, ssrc, invd, A0);
  k_gemm<<<MT64 * 4, 256, 0, stream>>>(A0, 64, Bt0, 64, A1, 1024, b0, 1, 4);

  // layer 1: agg(h0) -> A1[:, 512:], h1 = relu(A1 @ [Ws1;Wn1] + b1) -> A2[:, :512]
  k_agg512<<<(NN + 3) / 4, 256, 0, stream>>>(A1, rp, ssrc, invd);
  k_gemm<<<MT64 * 4, 256, 0, stream>>>(A1, 1024, Bt1, 1024, A2, 1024, b1, 1, 4);

  // layer 2 (fused by linearity): agg(h1) -> A2[:, 512:],
  // out = A2 @ [Ws2;Wn2] + b2   (== h1@Ws2 + mean_agg(h1)@Wn2 + b2)
  k_agg512<<<(NN + 3) / 4, 256, 0, stream>>>(A2, rp, ssrc, invd);
  k_gemm<<<MT64 * 2, 256, 0, stream>>>(A2, 1024, BtSN2, 1024, out_h, 256, b2, 2, 2);

  // avg pooling per graph (graph_ids sorted; NG*8 blocks + pre-scaled atomics)
  k_pool<<<NG * 8, 256, 0, stream>>>(out_h, gid, out_hg);
}